// Round 20
// baseline (112.034 us; speedup 1.0000x reference)
//
#include <hip/hip_runtime.h>
#include <cmath>

#define IMG_H 512
#define IMG_W 512
#define TH 22            // tile rows = 2 chunks x 11 (straight-line r13 chunk body)
#define TW 64            // tile cols
#define LDSW 75          // ODD element stride (load-bearing); 74 used cols + 1 pad
#define GY 24            // ceil(512/22); last block has 6 valid rows
#define NPLANES 96       // 32 batch * 3 channels
#define NPIX 25165824.0  // 96*512*512

typedef float vf2 __attribute__((ext_vector_type(2)));

struct GaussW { float w[11]; };

// 4-array algebraic form (round 11): convolve (A,B) and (T,S), T = a^2+b^2.
// Round 20: OCCUPANCY VIA TH, NOT VIA BODY CHANGES. TH=22 keeps the proven
// straight-line 11-row chunk (21 staged loads, 52-VGPR natural allocation --
// r14-16 showed it's the LOOPED body, not launch bounds, that triggers
// remat/spill) while LDS drops to 26.4 KB -> 6 blocks/CU = 24 waves (+50%
// latency hiding). Total global loads invariant (2 chunks x 24 yblocks ==
// 3 x 16). Idle thread-slots park as whole waves at the barrier; 6 staggered
// blocks keep the CU issue pipes fed.
__global__ __launch_bounds__(256, 4) void ssim_main(
    const float* __restrict__ img1, const float* __restrict__ img2,
    float* __restrict__ partials, GaussW gw, int use_atomic, float* __restrict__ out)
{
    __shared__ vf2 VAB[TH][LDSW];   // 13200 B
    __shared__ vf2 VTS[TH][LDSW];   // 13200 B  (total 26.4 KB -> 6 blocks/CU)
    __shared__ float wsum[4];

    const int tid = threadIdx.x;
    const int plane = blockIdx.z;
    const int tr0 = blockIdx.y * TH;
    const int tc0 = blockIdx.x * TW;
    const float* __restrict__ plane1 = img1 + ((size_t)plane << 18);  // uniform -> SGPR base
    const float* __restrict__ plane2 = img2 + ((size_t)plane << 18);

    // ---------------- Phase 1: vertical conv, packed accumulator scatter ------
    // 2 chunks x 74 threads (tid<148): one lds column j (gc = tc0 + j - 5),
    // 11 output rows per chunk. Straight-line body identical to round 13.
    {
        const int j = tid % 74;
        const int chunk = tid / 74;   // 0..3; active if chunk<2
        if (chunk < 2) {
            const int r0 = chunk * 11;
            const int gc = tc0 + j - 5;
            const float cmask = ((unsigned)gc < IMG_W) ? 1.f : 0.f;
            const int gcc = min(max(gc, 0), IMG_W - 1);   // v_med3

            // ---- stage ALL loads first: one latency exposure, 42 in flight ----
            float ra[21], rb[21];
            #pragma unroll
            for (int ii = 0; ii < 21; ++ii) {
                const int gr = tr0 + r0 - 5 + ii;
                const int grc = min(max(gr, 0), IMG_H - 1);
                const uint32_t idx = (uint32_t)(grc * IMG_W + gcc);
                ra[ii] = plane1[idx];
                rb[ii] = plane2[idx];
            }
            __builtin_amdgcn_sched_barrier(0);   // pin load issue before tap stream

            vf2 aAB[11], aTS[11];
            #pragma unroll
            for (int ii = 0; ii < 21; ++ii) {
                const int gr = tr0 + r0 - 5 + ii;
                const float rmask = ((unsigned)gr < IMG_H) ? cmask : 0.f;
                const float a = ra[ii] * rmask;
                const float b = rb[ii] * rmask;
                const vf2 ab = { a, b };
                const vf2 pq = ab * ab;                    // v_pk_mul_f32
                const vf2 ts = { pq.x + pq.y, a * b };     // (a^2+b^2, a*b)
                #pragma unroll
                for (int o = 0; o < 11; ++o) {
                    if (o <= ii && ii <= o + 10) {          // compile-time predicate
                        const float wt = gw.w[ii - o];
                        const vf2 wtv = { wt, wt };
                        if (ii == o) {                       // first touch
                            aAB[o] = wtv * ab;
                            aTS[o] = wtv * ts;
                        } else {
                            aAB[o] = __builtin_elementwise_fma(wtv, ab, aAB[o]);
                            aTS[o] = __builtin_elementwise_fma(wtv, ts, aTS[o]);
                        }
                    }
                }
            }
            #pragma unroll
            for (int o = 0; o < 11; ++o) {
                VAB[r0 + o][j] = aAB[o];        // ds_write_b64
                VTS[r0 + o][j] = aTS[o];        // ds_write_b64
            }
        }
    }
    __syncthreads();

    // ---------------- Phase 2: horizontal conv, packed per-column scatter -----
    // r = tid&31 (LOW bits): b64 pair (75rr + c0 + k) mod 16 covers all 16
    // pairs (75 odd) = hw minimum. Rows 22..31 clamp their read row (keeps
    // addresses in-bounds) and mask their contribution; last y-block also
    // masks rows >= 512.
    float lsum = 0.f;
    {
        const int r = tid & 31;
        const int rr = min(r, TH - 1);         // clamp read row (in-bounds)
        const int c0 = (tid >> 5) * 8;         // col group 0..7
        const float vmask = (r < TH && tr0 + r < IMG_H) ? 1.f : 0.f;
        const vf2* __restrict__ bAB = &VAB[rr][c0];
        const vf2* __restrict__ bTS = &VTS[rr][c0];

        vf2 mAB[8], eTS[8];

        #pragma unroll
        for (int k = 0; k <= 17; ++k) {          // stored cols c0 .. c0+17
            const vf2 vab = bAB[k];              // ds_read_b64, immediate offset
            const vf2 vts = bTS[k];              // ds_read_b64
            #pragma unroll
            for (int c = 0; c < 8; ++c) {
                if (k - 10 <= c && c <= k) {                // compile-time
                    const float wt = gw.w[k - c];
                    const vf2 wtv = { wt, wt };
                    if (k == c) {                            // first touch (tap 0)
                        mAB[c] = wtv * vab;
                        eTS[c] = wtv * vts;
                    } else {
                        mAB[c] = __builtin_elementwise_fma(wtv, vab, mAB[c]);
                        eTS[c] = __builtin_elementwise_fma(wtv, vts, eTS[c]);
                    }
                }
            }
        }
        float tsum = 0.f;
        #pragma unroll
        for (int c = 0; c < 8; ++c) {
            const float a1 = mAB[c].x, a2 = mAB[c].y;   // mu1, mu2
            const float T  = eTS[c].x, S = eTS[c].y;    // conv(a^2+b^2), conv(ab)
            const float h    = fmaf(a1, a1, a2 * a2);   // mu11 + mu22
            const float mu12 = a1 * a2;
            const float num  = fmaf(2.f, mu12, 0.0001f)
                             * fmaf(2.f, S - mu12, 0.0009f);   // (2mu12+C1)(2s12+C2)
            const float den  = (h + 0.0001f) * ((T - h) + 0.0009f);
            tsum = fmaf(num, __builtin_amdgcn_rcpf(den), tsum); // rcp ~1ulp
        }
        lsum = tsum * vmask;
    }
    // block reduction
    #pragma unroll
    for (int off = 32; off; off >>= 1) lsum += __shfl_down(lsum, off, 64);
    if ((tid & 63) == 0) wsum[tid >> 6] = lsum;
    __syncthreads();
    if (tid == 0) {
        const float bs = wsum[0] + wsum[1] + wsum[2] + wsum[3];
        if (use_atomic) {
            atomicAdd(out, bs * (float)(1.0 / NPIX));
        } else {
            const int bId = (blockIdx.z * gridDim.y + blockIdx.y) * gridDim.x + blockIdx.x;
            partials[bId] = bs;
        }
    }
}

__global__ __launch_bounds__(256) void ssim_reduce(
    const float* __restrict__ partials, int n, float* __restrict__ out)
{
    const int tid = threadIdx.x;
    double s = 0.0;
    for (int i = tid; i < n; i += 256) s += (double)partials[i];
    #pragma unroll
    for (int off = 32; off; off >>= 1) s += __shfl_down(s, off, 64);
    __shared__ double ws[4];
    if ((tid & 63) == 0) ws[tid >> 6] = s;
    __syncthreads();
    if (tid == 0) out[0] = (float)(((ws[0] + ws[1]) + (ws[2] + ws[3])) / NPIX);
}

extern "C" void kernel_launch(void* const* d_in, const int* in_sizes, int n_in,
                              void* d_out, int out_size, void* d_ws, size_t ws_size,
                              hipStream_t stream) {
    const float* img1 = (const float*)d_in[0];
    const float* img2 = (const float*)d_in[1];
    float* out = (float*)d_out;

    // Gaussian window (host, double precision, normalized)
    GaussW gw;
    {
        double g[11], sum = 0.0;
        for (int i = 0; i < 11; ++i) {
            const double c = (double)(i - 5);
            g[i] = std::exp(-(c * c) / 4.5);   // 2*sigma^2 = 4.5
            sum += g[i];
        }
        for (int i = 0; i < 11; ++i) gw.w[i] = (float)(g[i] / sum);
    }

    dim3 grid(IMG_W / TW, GY, NPLANES);   // 8 x 24 x 96 = 18432
    const int nPart = grid.x * grid.y * grid.z;

    if (ws_size >= (size_t)nPart * sizeof(float)) {
        // deterministic two-stage reduction
        ssim_main<<<grid, 256, 0, stream>>>(img1, img2, (float*)d_ws, gw, 0, out);
        ssim_reduce<<<1, 256, 0, stream>>>((float*)d_ws, nPart, out);
    } else {
        // fallback: atomic accumulation (still within tolerance)
        hipMemsetAsync(d_out, 0, sizeof(float), stream);
        ssim_main<<<grid, 256, 0, stream>>>(img1, img2, nullptr, gw, 1, out);
    }
}

// Round 21
// 103.201 us; speedup vs baseline: 1.0856x; 1.0856x over previous
//
#include <hip/hip_runtime.h>
#include <cmath>

#define IMG_H 512
#define IMG_W 512
#define TH 32            // tile rows (phase-2 r=tid&31 EXACT -- no row waste, r20 lesson)
#define TW 48            // output cols per block
#define SCOLS 58         // stored cols = TW + 10 halo
#define LDSW 59          // ODD element stride; 59 mod 16 = 11 -> b64 pair bijective over rows
#define GX 11            // ceil(512/48); last block outputs 32 cols (masked, ~3% waste)
#define NPLANES 96       // 32 batch * 3 channels
#define NPIX 25165824.0  // 96*512*512

typedef float vf2 __attribute__((ext_vector_type(2)));

struct GaussW { float w[11]; };

// 4-array algebraic form (round 11): convolve (A,B) and (T,S), T = a^2+b^2.
// Round 21: occupancy via TILE WIDTH. TW=48 -> LDS 30.2 KB -> 5 blocks/CU
// (20 waves, +25% latency hiding) while keeping:
//   - TH=32: phase-2 row mapping exact (r20's TH=22 wasted 45% of ph2 taps)
//   - the straight-line r13 11-row chunk body (52-VGPR natural allocation)
//   - launch_bounds cap ~96 > 52 (r14: cap < body's need = spill)
// r20 proved the stall term is occupancy-curable (VALUBusy 87-92% at 24
// waves); this buys occupancy with only +7.8% L2-hot halo loads.
__global__ __launch_bounds__(256, 5) void ssim_main(
    const float* __restrict__ img1, const float* __restrict__ img2,
    float* __restrict__ partials, GaussW gw, int use_atomic, float* __restrict__ out)
{
    __shared__ vf2 VAB[TH][LDSW];   // 15104 B
    __shared__ vf2 VTS[TH][LDSW];   // 15104 B  (total 30.2 KB -> 5 blocks/CU)
    __shared__ float wsum[4];

    const int tid = threadIdx.x;
    const int plane = blockIdx.z;
    const int tr0 = blockIdx.y * TH;
    const int tc0 = blockIdx.x * TW;
    const float* __restrict__ plane1 = img1 + ((size_t)plane << 18);  // uniform -> SGPR base
    const float* __restrict__ plane2 = img2 + ((size_t)plane << 18);

    // ---------------- Phase 1: vertical conv, packed accumulator scatter ------
    // 3 chunks x 58 active threads (j = tid&63 < 58, chunk = tid>>6 < 3):
    // one lds column j (gc = tc0 + j - 5), 11 output rows per chunk.
    // Straight-line body identical to round 13. 4th wave parks at barrier.
    {
        const int j = tid & 63;
        const int chunk = tid >> 6;   // 0..3; active if chunk<3 && j<58
        if (chunk < 3 && j < SCOLS) {
            const int r0 = chunk * 11;
            const int gc = tc0 + j - 5;
            const float cmask = ((unsigned)gc < IMG_W) ? 1.f : 0.f;
            const int gcc = min(max(gc, 0), IMG_W - 1);   // v_med3

            // ---- stage ALL loads first: one latency exposure, 42 in flight ----
            float ra[21], rb[21];
            #pragma unroll
            for (int ii = 0; ii < 21; ++ii) {
                const int gr = tr0 + r0 - 5 + ii;
                const int grc = min(max(gr, 0), IMG_H - 1);
                const uint32_t idx = (uint32_t)(grc * IMG_W + gcc);
                ra[ii] = plane1[idx];
                rb[ii] = plane2[idx];
            }
            __builtin_amdgcn_sched_barrier(0);   // pin load issue before tap stream

            vf2 aAB[11], aTS[11];
            #pragma unroll
            for (int ii = 0; ii < 21; ++ii) {
                const int gr = tr0 + r0 - 5 + ii;
                const float rmask = ((unsigned)gr < IMG_H) ? cmask : 0.f;
                const float a = ra[ii] * rmask;
                const float b = rb[ii] * rmask;
                const vf2 ab = { a, b };
                const vf2 pq = ab * ab;                    // v_pk_mul_f32
                const vf2 ts = { pq.x + pq.y, a * b };     // (a^2+b^2, a*b)
                #pragma unroll
                for (int o = 0; o < 11; ++o) {
                    if (o <= ii && ii <= o + 10) {          // compile-time predicate
                        const float wt = gw.w[ii - o];
                        const vf2 wtv = { wt, wt };
                        if (ii == o) {                       // first touch
                            aAB[o] = wtv * ab;
                            aTS[o] = wtv * ts;
                        } else {
                            aAB[o] = __builtin_elementwise_fma(wtv, ab, aAB[o]);
                            aTS[o] = __builtin_elementwise_fma(wtv, ts, aTS[o]);
                        }
                    }
                }
            }
            #pragma unroll
            for (int o = 0; o < 11; ++o) {
                const int r = r0 + o;
                if (r0 + o < TH) {   // only chunk2/o=10 is false
                    VAB[r][j] = aAB[o];        // ds_write_b64
                    VTS[r][j] = aTS[o];        // ds_write_b64
                }
            }
        }
    }
    __syncthreads();

    // ---------------- Phase 2: horizontal conv, packed per-column scatter -----
    // r = tid&31 (LOW bits): b64 pair (59r + c0 + k) mod 16 bijective over r
    // (59 odd) -> all 16 pairs x2 per half-wave = hardware minimum.
    // 8 col-groups x 6 outputs = 48; last x-block masks cols >= cvalid.
    float lsum = 0.f;
    {
        const int r = tid & 31;        // 0..31  (low bits!)
        const int c0 = (tid >> 5) * 6; // col group 0..7, 6 outputs each
        const vf2* __restrict__ bAB = &VAB[r][c0];
        const vf2* __restrict__ bTS = &VTS[r][c0];
        const int cvalid = min(TW, IMG_W - tc0);   // 48, or 32 for last block

        vf2 mAB[6], eTS[6];

        #pragma unroll
        for (int k = 0; k <= 15; ++k) {          // stored cols c0 .. c0+15
            const vf2 vab = bAB[k];              // ds_read_b64, immediate offset
            const vf2 vts = bTS[k];              // ds_read_b64
            #pragma unroll
            for (int c = 0; c < 6; ++c) {
                if (k - 10 <= c && c <= k) {                // compile-time
                    const float wt = gw.w[k - c];
                    const vf2 wtv = { wt, wt };
                    if (k == c) {                            // first touch (tap 0)
                        mAB[c] = wtv * vab;
                        eTS[c] = wtv * vts;
                    } else {
                        mAB[c] = __builtin_elementwise_fma(wtv, vab, mAB[c]);
                        eTS[c] = __builtin_elementwise_fma(wtv, vts, eTS[c]);
                    }
                }
            }
        }
        #pragma unroll
        for (int c = 0; c < 6; ++c) {
            const float a1 = mAB[c].x, a2 = mAB[c].y;   // mu1, mu2
            const float T  = eTS[c].x, S = eTS[c].y;    // conv(a^2+b^2), conv(ab)
            const float h    = fmaf(a1, a1, a2 * a2);   // mu11 + mu22
            const float mu12 = a1 * a2;
            const float num  = fmaf(2.f, mu12, 0.0001f)
                             * fmaf(2.f, S - mu12, 0.0009f);   // (2mu12+C1)(2s12+C2)
            const float den  = (h + 0.0001f) * ((T - h) + 0.0009f);
            const float val  = num * __builtin_amdgcn_rcpf(den);  // rcp ~1ulp
            lsum += (c0 + c < cvalid) ? val : 0.f;
        }
    }
    // block reduction
    #pragma unroll
    for (int off = 32; off; off >>= 1) lsum += __shfl_down(lsum, off, 64);
    if ((tid & 63) == 0) wsum[tid >> 6] = lsum;
    __syncthreads();
    if (tid == 0) {
        const float bs = wsum[0] + wsum[1] + wsum[2] + wsum[3];
        if (use_atomic) {
            atomicAdd(out, bs * (float)(1.0 / NPIX));
        } else {
            const int bId = (blockIdx.z * gridDim.y + blockIdx.y) * gridDim.x + blockIdx.x;
            partials[bId] = bs;
        }
    }
}

__global__ __launch_bounds__(256) void ssim_reduce(
    const float* __restrict__ partials, int n, float* __restrict__ out)
{
    const int tid = threadIdx.x;
    double s = 0.0;
    for (int i = tid; i < n; i += 256) s += (double)partials[i];
    #pragma unroll
    for (int off = 32; off; off >>= 1) s += __shfl_down(s, off, 64);
    __shared__ double ws[4];
    if ((tid & 63) == 0) ws[tid >> 6] = s;
    __syncthreads();
    if (tid == 0) out[0] = (float)(((ws[0] + ws[1]) + (ws[2] + ws[3])) / NPIX);
}

extern "C" void kernel_launch(void* const* d_in, const int* in_sizes, int n_in,
                              void* d_out, int out_size, void* d_ws, size_t ws_size,
                              hipStream_t stream) {
    const float* img1 = (const float*)d_in[0];
    const float* img2 = (const float*)d_in[1];
    float* out = (float*)d_out;

    // Gaussian window (host, double precision, normalized)
    GaussW gw;
    {
        double g[11], sum = 0.0;
        for (int i = 0; i < 11; ++i) {
            const double c = (double)(i - 5);
            g[i] = std::exp(-(c * c) / 4.5);   // 2*sigma^2 = 4.5
            sum += g[i];
        }
        for (int i = 0; i < 11; ++i) gw.w[i] = (float)(g[i] / sum);
    }

    dim3 grid(GX, IMG_H / TH, NPLANES);   // 11 x 16 x 96 = 16896
    const int nPart = grid.x * grid.y * grid.z;

    if (ws_size >= (size_t)nPart * sizeof(float)) {
        // deterministic two-stage reduction
        ssim_main<<<grid, 256, 0, stream>>>(img1, img2, (float*)d_ws, gw, 0, out);
        ssim_reduce<<<1, 256, 0, stream>>>((float*)d_ws, nPart, out);
    } else {
        // fallback: atomic accumulation (still within tolerance)
        hipMemsetAsync(d_out, 0, sizeof(float), stream);
        ssim_main<<<grid, 256, 0, stream>>>(img1, img2, nullptr, gw, 1, out);
    }
}

// Round 22
// 90.242 us; speedup vs baseline: 1.2415x; 1.1436x over previous
//
#include <hip/hip_runtime.h>
#include <cmath>

#define IMG_H 512
#define IMG_W 512
#define TH 32            // tile rows (proven base)
#define TW 64            // tile cols
#define LDSW 75          // ODD element stride (load-bearing!); 74 used cols + 1 pad
#define NPLANES 96       // 32 batch * 3 channels
#define NPIX 25165824.0  // 96*512*512

typedef float vf2 __attribute__((ext_vector_type(2)));

struct GaussW { float w[11]; };

// FINAL: ROUND-13/19 CONFIGURATION (empirical optimum, 90.1-90.7 us wall).
// 4-array algebraic form: convolve (A,B) and (T,S), T = a^2+b^2:
//   den = (mu1^2+mu2^2+C1) * ((conv(T) - mu1^2 - mu2^2) + C2)
// Proven invariants: 11 rows/thread (1.9 loads/row), issue-clustered 42-load
// stream (sched_barrier), 52-VGPR natural allocation, 4 blocks/CU, odd-75
// stride (bank-conflict zero), pk_fma taps via __builtin_elementwise_fma.
// Exhaustive neighborhood (r14-r21) all measured worse:
//   r14 8blk+staging: spill (WRITE 288MB)  | r15 8blk: remat (FETCH +47%)
//   r16 bounds(6): identical codegen null  | r17 R=4 tasks: +1.6 loads/row
//   r18 wave-uniform rows: 3.5x load redun | r20 TH=22: 45% ph2 row waste
//   r21 TW=48: FETCH +34% (halo/line tax)
__global__ __launch_bounds__(256, 4) void ssim_main(
    const float* __restrict__ img1, const float* __restrict__ img2,
    float* __restrict__ partials, GaussW gw, int use_atomic, float* __restrict__ out)
{
    __shared__ vf2 VAB[TH][LDSW];   // 19200 B
    __shared__ vf2 VTS[TH][LDSW];   // 19200 B  (total 38.4 KB -> 4 blocks/CU)
    __shared__ float wsum[4];

    const int tid = threadIdx.x;
    const int plane = blockIdx.z;
    const int tr0 = blockIdx.y * TH;
    const int tc0 = blockIdx.x * TW;
    const float* __restrict__ plane1 = img1 + ((size_t)plane << 18);  // uniform -> SGPR base
    const float* __restrict__ plane2 = img2 + ((size_t)plane << 18);

    // ---------------- Phase 1: vertical conv, packed accumulator scatter ------
    // 3 chunks x 74 active threads: one lds column j (gc = tc0 + j - 5) each,
    // 11 output rows per chunk. Single code path, first-touch init.
    {
        const int j = tid % 80;       // lds col
        const int chunk = tid / 80;   // 0..2; active if chunk<3 && j<74
        if (chunk < 3 && j < 74) {
            const int r0 = chunk * 11;
            const int gc = tc0 + j - 5;
            const float cmask = ((unsigned)gc < IMG_W) ? 1.f : 0.f;
            const int gcc = min(max(gc, 0), IMG_W - 1);   // v_med3

            // ---- stage ALL loads first: one latency exposure, 42 in flight ----
            float ra[21], rb[21];
            #pragma unroll
            for (int ii = 0; ii < 21; ++ii) {
                const int gr = tr0 + r0 - 5 + ii;
                const int grc = min(max(gr, 0), IMG_H - 1);
                const uint32_t idx = (uint32_t)(grc * IMG_W + gcc);
                ra[ii] = plane1[idx];
                rb[ii] = plane2[idx];
            }
            __builtin_amdgcn_sched_barrier(0);   // pin load issue before tap stream

            vf2 aAB[11], aTS[11];
            #pragma unroll
            for (int ii = 0; ii < 21; ++ii) {
                const int gr = tr0 + r0 - 5 + ii;
                const float rmask = ((unsigned)gr < IMG_H) ? cmask : 0.f;
                const float a = ra[ii] * rmask;
                const float b = rb[ii] * rmask;
                const vf2 ab = { a, b };
                const vf2 pq = ab * ab;                    // v_pk_mul_f32
                const vf2 ts = { pq.x + pq.y, a * b };     // (a^2+b^2, a*b)
                #pragma unroll
                for (int o = 0; o < 11; ++o) {
                    if (o <= ii && ii <= o + 10) {          // compile-time predicate
                        const float wt = gw.w[ii - o];
                        const vf2 wtv = { wt, wt };
                        if (ii == o) {                       // first touch
                            aAB[o] = wtv * ab;
                            aTS[o] = wtv * ts;
                        } else {
                            aAB[o] = __builtin_elementwise_fma(wtv, ab, aAB[o]);
                            aTS[o] = __builtin_elementwise_fma(wtv, ts, aTS[o]);
                        }
                    }
                }
            }
            #pragma unroll
            for (int o = 0; o < 11; ++o) {
                const int r = r0 + o;
                if (r0 + o < TH) {   // only chunk2/o=10 is false
                    VAB[r][j] = aAB[o];        // ds_write_b64
                    VTS[r][j] = aTS[o];        // ds_write_b64
                }
            }
        }
    }
    __syncthreads();

    // ---------------- Phase 2: horizontal conv, packed per-column scatter -----
    // Row index in LOW lane bits: b64 pair (75r + c0 + k) mod 16, 75 odd ->
    // all 16 pairs x2 per half-wave = hardware minimum, conflict-free.
    float lsum = 0.f;
    {
        const int r = tid & 31;        // 0..31  (low bits!)
        const int c0 = (tid >> 5) * 8; // col group 0..7
        const vf2* __restrict__ bAB = &VAB[r][c0];
        const vf2* __restrict__ bTS = &VTS[r][c0];

        vf2 mAB[8], eTS[8];

        #pragma unroll
        for (int k = 0; k <= 17; ++k) {          // stored cols c0 .. c0+17
            const vf2 vab = bAB[k];              // ds_read_b64, immediate offset
            const vf2 vts = bTS[k];              // ds_read_b64
            #pragma unroll
            for (int c = 0; c < 8; ++c) {
                if (k - 10 <= c && c <= k) {                // compile-time
                    const float wt = gw.w[k - c];
                    const vf2 wtv = { wt, wt };
                    if (k == c) {                            // first touch (tap 0)
                        mAB[c] = wtv * vab;
                        eTS[c] = wtv * vts;
                    } else {
                        mAB[c] = __builtin_elementwise_fma(wtv, vab, mAB[c]);
                        eTS[c] = __builtin_elementwise_fma(wtv, vts, eTS[c]);
                    }
                }
            }
        }
        #pragma unroll
        for (int c = 0; c < 8; ++c) {
            const float a1 = mAB[c].x, a2 = mAB[c].y;   // mu1, mu2
            const float T  = eTS[c].x, S = eTS[c].y;    // conv(a^2+b^2), conv(ab)
            const float h    = fmaf(a1, a1, a2 * a2);   // mu11 + mu22
            const float mu12 = a1 * a2;
            const float num  = fmaf(2.f, mu12, 0.0001f)
                             * fmaf(2.f, S - mu12, 0.0009f);   // (2mu12+C1)(2s12+C2)
            const float den  = (h + 0.0001f) * ((T - h) + 0.0009f);
            lsum = fmaf(num, __builtin_amdgcn_rcpf(den), lsum); // rcp ~1ulp, tol 2.7e-4
        }
    }
    // block reduction
    #pragma unroll
    for (int off = 32; off; off >>= 1) lsum += __shfl_down(lsum, off, 64);
    if ((tid & 63) == 0) wsum[tid >> 6] = lsum;
    __syncthreads();
    if (tid == 0) {
        const float bs = wsum[0] + wsum[1] + wsum[2] + wsum[3];
        if (use_atomic) {
            atomicAdd(out, bs * (float)(1.0 / NPIX));
        } else {
            const int bId = (blockIdx.z * gridDim.y + blockIdx.y) * gridDim.x + blockIdx.x;
            partials[bId] = bs;
        }
    }
}

__global__ __launch_bounds__(256) void ssim_reduce(
    const float* __restrict__ partials, int n, float* __restrict__ out)
{
    const int tid = threadIdx.x;
    double s = 0.0;
    for (int i = tid; i < n; i += 256) s += (double)partials[i];
    #pragma unroll
    for (int off = 32; off; off >>= 1) s += __shfl_down(s, off, 64);
    __shared__ double ws[4];
    if ((tid & 63) == 0) ws[tid >> 6] = s;
    __syncthreads();
    if (tid == 0) out[0] = (float)(((ws[0] + ws[1]) + (ws[2] + ws[3])) / NPIX);
}

extern "C" void kernel_launch(void* const* d_in, const int* in_sizes, int n_in,
                              void* d_out, int out_size, void* d_ws, size_t ws_size,
                              hipStream_t stream) {
    const float* img1 = (const float*)d_in[0];
    const float* img2 = (const float*)d_in[1];
    float* out = (float*)d_out;

    // Gaussian window (host, double precision, normalized)
    GaussW gw;
    {
        double g[11], sum = 0.0;
        for (int i = 0; i < 11; ++i) {
            const double c = (double)(i - 5);
            g[i] = std::exp(-(c * c) / 4.5);   // 2*sigma^2 = 4.5
            sum += g[i];
        }
        for (int i = 0; i < 11; ++i) gw.w[i] = (float)(g[i] / sum);
    }

    dim3 grid(IMG_W / TW, IMG_H / TH, NPLANES);   // 8 x 16 x 96 = 12288
    const int nPart = grid.x * grid.y * grid.z;

    if (ws_size >= (size_t)nPart * sizeof(float)) {
        // deterministic two-stage reduction
        ssim_main<<<grid, 256, 0, stream>>>(img1, img2, (float*)d_ws, gw, 0, out);
        ssim_reduce<<<1, 256, 0, stream>>>((float*)d_ws, nPart, out);
    } else {
        // fallback: atomic accumulation (still within tolerance)
        hipMemsetAsync(d_out, 0, sizeof(float), stream);
        ssim_main<<<grid, 256, 0, stream>>>(img1, img2, nullptr, gw, 1, out);
    }
}